// Round 3
// baseline (362.241 us; speedup 1.0000x reference)
//
#include <hip/hip_runtime.h>
#include <hip/hip_bf16.h>

// Problem constants (from reference)
#define N_NODES 50000
#define D_FEAT  128
#define N_EDGES 600000
#define HIDDEN  256
#define K_DIM   256   // 2*D_FEAT

typedef __attribute__((ext_vector_type(8))) short bf16x8;   // 8 bf16 = 4 VGPRs
typedef __attribute__((ext_vector_type(4))) float f32x4;    // MFMA acc

__device__ __forceinline__ unsigned short f32_to_bf16(float f) {
    unsigned int u = __float_as_uint(f);
    unsigned int r = (u + 0x7fffu + ((u >> 16) & 1u)) >> 16;  // RNE
    return (unsigned short)r;
}
__device__ __forceinline__ float bf16_to_f32(unsigned short u) {
    return __uint_as_float(((unsigned int)u) << 16);
}
__device__ __forceinline__ unsigned int pack_bf16x2(float lo, float hi) {
    return (unsigned int)f32_to_bf16(lo) | ((unsigned int)f32_to_bf16(hi) << 16);
}

// ---------------------------------------------------------------------------
// Packed bf16x2 atomic add: native pk_add_bf16 if the HIP header provides the
// overload (SFINAE), else a CAS loop. Both are device-scope correct.
// ---------------------------------------------------------------------------
__device__ __forceinline__ void cas_pk_add(unsigned int* p, float f0, float f1) {
    unsigned int old = *p;
    while (true) {
        float s0 = bf16_to_f32((unsigned short)(old & 0xffffu)) + f0;
        float s1 = bf16_to_f32((unsigned short)(old >> 16)) + f1;
        unsigned int nv = pack_bf16x2(s0, s1);
        unsigned int prev = atomicCAS(p, old, nv);
        if (prev == old) break;
        old = prev;
    }
}

template <typename T>
__device__ __forceinline__ auto pk_add_impl(T* p, float f0, float f1, int)
    -> decltype(atomicAdd((T*)0, T{}), void()) {
    T v;
    v.x = __float2bfloat16(f0);   // low word
    v.y = __float2bfloat16(f1);   // high word
    atomicAdd(p, v);
}
template <typename T>
__device__ __forceinline__ void pk_add_impl(T* p, float f0, float f1, long) {
    cas_pk_add((unsigned int*)p, f0, f1);
}
__device__ __forceinline__ void pk_add(unsigned int* p, float f0, float f1) {
    pk_add_impl((__hip_bfloat162*)p, f0, f1, 0);
}

// ---------------------------------------------------------------------------
// Repack W (f32 [256][256] row-major) into bf16 MFMA-B-fragment order:
// Wp[kt][n][quad][j]  (kt<8, n<256, quad<4, j<8), k = kt*32 + quad*8 + j,
// so lane (n = lane&15 within tile, quad = lane>>4) reads 16 contiguous bytes.
// ---------------------------------------------------------------------------
__global__ __launch_bounds__(256) void repack_w(
    const float* __restrict__ W, unsigned short* __restrict__ Wp) {
    int t = blockIdx.x * 256 + threadIdx.x;      // 65536 total
    int kt = t >> 13;
    int n  = (t >> 5) & 255;
    int q  = (t >> 3) & 3;
    int j  = t & 7;
    int k  = kt * 32 + q * 8 + j;
    Wp[t] = f32_to_bf16(W[k * 256 + n]);
}

// ---------------------------------------------------------------------------
// Edge scatter: one edge per wave. Each lane handles 2 features (float2 load
// = 8B/lane, one packed-bf16 atomic). Lane 0 bumps the receiver count.
// sums is [N][64] u32 (packed bf16 pairs), counts is [N] u32.
// ---------------------------------------------------------------------------
__global__ __launch_bounds__(256) void scatter_edges(
    const float* __restrict__ nodes,
    const int* __restrict__ senders,
    const int* __restrict__ receivers,
    unsigned int* __restrict__ sums32,
    unsigned int* __restrict__ counts) {
    int e    = blockIdx.x * 4 + (threadIdx.x >> 6);   // 4 waves/block, 1 edge/wave
    int lane = threadIdx.x & 63;
    int s = senders[e];
    int r = receivers[e];
    const float2 v = *(const float2*)(nodes + (size_t)s * D_FEAT + lane * 2);
    pk_add(&sums32[(size_t)r * 64 + lane], v.x, v.y);
    if (lane == 0) atomicAdd(&counts[r], 1u);
}

// ---------------------------------------------------------------------------
// Fused mean + concat + GEMM + bias + relu.
// Block: 256 threads (4 waves), tile = 64 nodes x 256 hidden.
// h[64][256] staged in LDS as bf16, row stride 264 u16 (pad 8 -> only 2-way
// bank alias, free). Wave w computes N-columns [64w, 64w+64): 4x4 tiles of
// mfma_f32_16x16x32_bf16 over K=256 (8 iters). Output stores are f32.
// ---------------------------------------------------------------------------
#define H_STRIDE 264   // u16 units; 132 u32 units

__global__ __launch_bounds__(256) void mean_gemm(
    const float* __restrict__ nodes,
    const unsigned int* __restrict__ sums32,
    const unsigned int* __restrict__ counts,
    const unsigned short* __restrict__ Wp,
    const float* __restrict__ bias,
    float* __restrict__ out) {
    __shared__ __align__(16) unsigned int h32[64 * (H_STRIDE / 2)];

    const int m0  = blockIdx.x * 64;
    const int tid = threadIdx.x;

    // ---- stage h = [bf16(sums)/max(count,1) | bf16(nodes)] into LDS ----
    for (int i = 0; i < 32; i++) {
        int p   = tid + i * 256;        // pair index in [0, 8192)
        int row = p >> 7;               // [0,64)
        int pc  = p & 127;              // pair-column [0,128)
        int m   = m0 + row;
        unsigned int packed = 0;
        if (m < N_NODES) {
            if (pc < 64) {
                unsigned int sv = sums32[(size_t)m * 64 + pc];
                float c   = (float)counts[m];
                float inv = 1.0f / fmaxf(c, 1.0f);
                float lo = bf16_to_f32((unsigned short)(sv & 0xffffu)) * inv;
                float hi = bf16_to_f32((unsigned short)(sv >> 16)) * inv;
                packed = pack_bf16x2(lo, hi);
            } else {
                const float2 nv =
                    *(const float2*)(nodes + (size_t)m * D_FEAT + (pc - 64) * 2);
                packed = pack_bf16x2(nv.x, nv.y);
            }
        }
        h32[row * (H_STRIDE / 2) + pc] = packed;
    }
    __syncthreads();

    const unsigned short* h = (const unsigned short*)h32;
    const int wave  = tid >> 6;
    const int lane  = tid & 63;
    const int nbase = wave * 64;
    const int rsel  = lane & 15;   // n (B/D) or m (A) within 16
    const int quad  = lane >> 4;   // k-group / row-group selector

    f32x4 acc[4][4] = {};

    for (int kk = 0; kk < K_DIM; kk += 32) {
        bf16x8 a[4], bw[4];
        // A fragments: A[m = rsel][k = quad*8 + j] from LDS rows
        #pragma unroll
        for (int mt = 0; mt < 4; mt++) {
            const unsigned short* pa =
                &h[(mt * 16 + rsel) * H_STRIDE + kk + quad * 8];
            a[mt] = *(const bf16x8*)pa;   // ds_read_b128
        }
        // B fragments: repacked Wp, 16B contiguous per lane
        int kt = kk >> 5;
        #pragma unroll
        for (int nt = 0; nt < 4; nt++) {
            int n = nbase + nt * 16 + rsel;
            bw[nt] = *(const bf16x8*)&Wp[kt * 8192 + n * 32 + quad * 8];
        }
        #pragma unroll
        for (int mt = 0; mt < 4; mt++)
            #pragma unroll
            for (int nt = 0; nt < 4; nt++)
                acc[mt][nt] = __builtin_amdgcn_mfma_f32_16x16x32_bf16(
                    a[mt], bw[nt], acc[mt][nt], 0, 0, 0);
    }

    // ---- epilogue: bias + relu, f32 store ----
    // C/D layout: col(n) = lane&15, row(m) = quad*4 + reg  [m89-verified]
    #pragma unroll
    for (int nt = 0; nt < 4; nt++) {
        int n = nbase + nt * 16 + rsel;
        float bn = bias[n];
        #pragma unroll
        for (int mt = 0; mt < 4; mt++) {
            #pragma unroll
            for (int r = 0; r < 4; r++) {
                int m = m0 + mt * 16 + quad * 4 + r;
                if (m < N_NODES) {
                    float v = acc[mt][nt][r] + bn;
                    out[(size_t)m * HIDDEN + n] = fmaxf(v, 0.0f);
                }
            }
        }
    }
}

// ---------------------------------------------------------------------------
extern "C" void kernel_launch(void* const* d_in, const int* in_sizes, int n_in,
                              void* d_out, int out_size, void* d_ws, size_t ws_size,
                              hipStream_t stream) {
    const float* nodes     = (const float*)d_in[0];   // f32 [N,128]
    const int*   senders   = (const int*)d_in[1];     // [E]
    const int*   receivers = (const int*)d_in[2];     // [E]
    const float* W         = (const float*)d_in[3];   // f32 [256,256]
    const float* bias      = (const float*)d_in[4];   // f32 [256]
    float*       out       = (float*)d_out;           // f32 [N,256]

    // workspace layout (total ~13.13 MB)
    unsigned int* sums32 = (unsigned int*)d_ws;                 // [N*64] packed bf16x2
    unsigned int* counts = sums32 + (size_t)N_NODES * 64;       // [N] u32
    unsigned short* Wp   = (unsigned short*)(counts + N_NODES); // [65536] bf16

    size_t zero_bytes = ((size_t)N_NODES * 64 + N_NODES) * sizeof(unsigned int);
    hipMemsetAsync(d_ws, 0, zero_bytes, stream);

    repack_w<<<dim3(65536 / 256), dim3(256), 0, stream>>>(W, Wp);

    scatter_edges<<<dim3(N_EDGES / 4), dim3(256), 0, stream>>>(
        nodes, senders, receivers, sums32, counts);

    int gemm_blocks = (N_NODES + 63) / 64;   // 782
    mean_gemm<<<dim3(gemm_blocks), dim3(256), 0, stream>>>(
        nodes, sums32, counts, Wp, bias, out);
}

// Round 4
// 300.510 us; speedup vs baseline: 1.2054x; 1.2054x over previous
//
#include <hip/hip_runtime.h>
#include <hip/hip_bf16.h>

// Problem constants (from reference)
#define N_NODES 50000
#define D_FEAT  128
#define N_EDGES 600000
#define HIDDEN  256
#define K_DIM   256   // 2*D_FEAT

typedef __attribute__((ext_vector_type(8))) short bf16x8;   // 8 bf16 = 4 VGPRs
typedef __attribute__((ext_vector_type(4))) float f32x4;    // MFMA acc

__device__ __forceinline__ unsigned short f32_to_bf16(float f) {
    unsigned int u = __float_as_uint(f);
    unsigned int r = (u + 0x7fffu + ((u >> 16) & 1u)) >> 16;  // RNE
    return (unsigned short)r;
}
__device__ __forceinline__ unsigned int pack_bf16x2(float lo, float hi) {
    return (unsigned int)f32_to_bf16(lo) | ((unsigned int)f32_to_bf16(hi) << 16);
}

// ---------------------------------------------------------------------------
// K2: per-receiver degree count (600k int atomics on 50k counters)
// ---------------------------------------------------------------------------
__global__ __launch_bounds__(256) void degree_count(
    const int* __restrict__ receivers, unsigned int* __restrict__ deg) {
    int e = blockIdx.x * 256 + threadIdx.x;
    if (e < N_EDGES) atomicAdd(&deg[receivers[e]], 1u);
}

// ---------------------------------------------------------------------------
// K3: exclusive scan of deg -> offsets[N+1]. Single block, 1024 threads,
// 49 nodes/thread (1024*49 = 50176 >= 50000). Two-pass chunk scan +
// Hillis-Steele over per-thread partials in LDS.
// ---------------------------------------------------------------------------
__global__ __launch_bounds__(1024) void scan_offsets(
    const unsigned int* __restrict__ deg, unsigned int* __restrict__ off) {
    __shared__ unsigned int part[1024];
    const int t  = threadIdx.x;
    const int CH = 49;
    int lo = t * CH;
    int hi = lo + CH; if (hi > N_NODES) hi = N_NODES;
    unsigned int s = 0;
    for (int i = lo; i < hi; i++) s += deg[i];
    part[t] = s;
    __syncthreads();
    // inclusive Hillis-Steele scan over 1024 partials
    for (int d = 1; d < 1024; d <<= 1) {
        unsigned int v = (t >= d) ? part[t - d] : 0u;
        __syncthreads();
        part[t] += v;
        __syncthreads();
    }
    unsigned int run = (t == 0) ? 0u : part[t - 1];
    for (int i = lo; i < hi; i++) {
        off[i] = run;
        run += deg[i];
    }
    if (t == 1023) off[N_NODES] = run;   // lo > N here, so run == total
}

// ---------------------------------------------------------------------------
// K4: CSR fill. slot = atomicAdd(cursor[r]); edge_src[off[r]+slot] = sender.
// ---------------------------------------------------------------------------
__global__ __launch_bounds__(256) void csr_fill(
    const int* __restrict__ senders, const int* __restrict__ receivers,
    const unsigned int* __restrict__ off, unsigned int* __restrict__ cursor,
    unsigned int* __restrict__ edge_src) {
    int e = blockIdx.x * 256 + threadIdx.x;
    if (e < N_EDGES) {
        int r = receivers[e];
        unsigned int slot = atomicAdd(&cursor[r], 1u);
        edge_src[off[r] + slot] = (unsigned int)senders[e];
    }
}

// ---------------------------------------------------------------------------
// K5: repack W (f32 [256][256] row-major) into bf16 MFMA-B-fragment order:
// Wp[kt][n][quad][j]  (kt<8, n<256, quad<4, j<8), k = kt*32 + quad*8 + j,
// so lane (n = lane&15 within tile, quad = lane>>4) reads 16 contiguous bytes.
// ---------------------------------------------------------------------------
__global__ __launch_bounds__(256) void repack_w(
    const float* __restrict__ W, unsigned short* __restrict__ Wp) {
    int t = blockIdx.x * 256 + threadIdx.x;      // 65536 total
    int kt = t >> 13;
    int n  = (t >> 5) & 255;
    int q  = (t >> 3) & 3;
    int j  = t & 7;
    int k  = kt * 32 + q * 8 + j;
    Wp[t] = f32_to_bf16(W[k * 256 + n]);
}

// ---------------------------------------------------------------------------
// K6: fused CSR-gather mean + concat + GEMM + bias + relu.
// Block: 256 threads (4 waves), tile = 64 nodes x 256 hidden.
// Phase A: wave w owns nodes [w*16, w*16+16): walks its edge lists with a
//   4-deep unrolled f32 register accumulator (4 independent 512B row-gathers
//   in flight). Lane l covers features {2l, 2l+1}. Writes bf16 h-tile to LDS.
// Phase B: 4x4 tiles of mfma_f32_16x16x32_bf16 over K=256 (verified R3).
// h row stride 264 u16 (132 u32): 2-way bank alias only (free).
// ---------------------------------------------------------------------------
#define H_STRIDE 264   // u16 units; 132 u32 units

__global__ __launch_bounds__(256) void gather_mean_gemm(
    const float* __restrict__ nodes,
    const unsigned int* __restrict__ off,
    const unsigned int* __restrict__ edge_src,
    const unsigned short* __restrict__ Wp,
    const float* __restrict__ bias,
    float* __restrict__ out) {
    __shared__ __align__(16) unsigned int h32[64 * (H_STRIDE / 2)];

    const int m0   = blockIdx.x * 64;
    const int tid  = threadIdx.x;
    const int wave = tid >> 6;
    const int lane = tid & 63;

    // ---- Phase A: gather + mean + self-features into LDS ----
    for (int i = 0; i < 16; i++) {
        int row = wave * 16 + i;
        int m   = m0 + row;
        float a0 = 0.f, a1 = 0.f, b0 = 0.f, b1 = 0.f;
        float c0 = 0.f, c1 = 0.f, d0 = 0.f, d1 = 0.f;
        float self0 = 0.f, self1 = 0.f;
        if (m < N_NODES) {
            unsigned int eb = off[m], ee = off[m + 1];
            unsigned int e = eb;
            for (; e + 4 <= ee; e += 4) {
                unsigned int sa = edge_src[e];
                unsigned int sb = edge_src[e + 1];
                unsigned int sc = edge_src[e + 2];
                unsigned int sd = edge_src[e + 3];
                float2 va = *(const float2*)(nodes + (size_t)sa * D_FEAT + lane * 2);
                float2 vb = *(const float2*)(nodes + (size_t)sb * D_FEAT + lane * 2);
                float2 vc = *(const float2*)(nodes + (size_t)sc * D_FEAT + lane * 2);
                float2 vd = *(const float2*)(nodes + (size_t)sd * D_FEAT + lane * 2);
                a0 += va.x; a1 += va.y;
                b0 += vb.x; b1 += vb.y;
                c0 += vc.x; c1 += vc.y;
                d0 += vd.x; d1 += vd.y;
            }
            for (; e < ee; e++) {
                unsigned int sa = edge_src[e];
                float2 va = *(const float2*)(nodes + (size_t)sa * D_FEAT + lane * 2);
                a0 += va.x; a1 += va.y;
            }
            float inv = 1.0f / fmaxf((float)(ee - eb), 1.0f);
            a0 = (a0 + b0 + c0 + d0) * inv;
            a1 = (a1 + b1 + c1 + d1) * inv;
            float2 sv = *(const float2*)(nodes + (size_t)m * D_FEAT + lane * 2);
            self0 = sv.x; self1 = sv.y;
        }
        h32[row * (H_STRIDE / 2) + lane]      = pack_bf16x2(a0, a1);
        h32[row * (H_STRIDE / 2) + 64 + lane] = pack_bf16x2(self0, self1);
    }
    __syncthreads();

    // ---- Phase B: MFMA GEMM (identical to R3-verified code) ----
    const unsigned short* h = (const unsigned short*)h32;
    const int nbase = wave * 64;
    const int rsel  = lane & 15;   // n (B/D) or m (A) within 16
    const int quad  = lane >> 4;   // k-group / row-group selector

    f32x4 acc[4][4] = {};

    for (int kk = 0; kk < K_DIM; kk += 32) {
        bf16x8 a[4], bw[4];
        #pragma unroll
        for (int mt = 0; mt < 4; mt++) {
            const unsigned short* pa =
                &h[(mt * 16 + rsel) * H_STRIDE + kk + quad * 8];
            a[mt] = *(const bf16x8*)pa;   // ds_read_b128
        }
        int kt = kk >> 5;
        #pragma unroll
        for (int nt = 0; nt < 4; nt++) {
            int n = nbase + nt * 16 + rsel;
            bw[nt] = *(const bf16x8*)&Wp[kt * 8192 + n * 32 + quad * 8];
        }
        #pragma unroll
        for (int mt = 0; mt < 4; mt++)
            #pragma unroll
            for (int nt = 0; nt < 4; nt++)
                acc[mt][nt] = __builtin_amdgcn_mfma_f32_16x16x32_bf16(
                    a[mt], bw[nt], acc[mt][nt], 0, 0, 0);
    }

    // epilogue: bias + relu, f32 store.  C/D: col(n)=lane&15, row(m)=quad*4+reg
    #pragma unroll
    for (int nt = 0; nt < 4; nt++) {
        int n = nbase + nt * 16 + rsel;
        float bn = bias[n];
        #pragma unroll
        for (int mt = 0; mt < 4; mt++) {
            #pragma unroll
            for (int r = 0; r < 4; r++) {
                int m = m0 + mt * 16 + quad * 4 + r;
                if (m < N_NODES) {
                    float v = acc[mt][nt][r] + bn;
                    out[(size_t)m * HIDDEN + n] = fmaxf(v, 0.0f);
                }
            }
        }
    }
}

// ---------------------------------------------------------------------------
extern "C" void kernel_launch(void* const* d_in, const int* in_sizes, int n_in,
                              void* d_out, int out_size, void* d_ws, size_t ws_size,
                              hipStream_t stream) {
    const float* nodes     = (const float*)d_in[0];   // f32 [N,128]
    const int*   senders   = (const int*)d_in[1];     // [E]
    const int*   receivers = (const int*)d_in[2];     // [E]
    const float* W         = (const float*)d_in[3];   // f32 [256,256]
    const float* bias      = (const float*)d_in[4];   // f32 [256]
    float*       out       = (float*)d_out;           // f32 [N,256]

    // workspace layout (~3.14 MB total)
    unsigned int* deg      = (unsigned int*)d_ws;              // [N]   (zeroed)
    unsigned int* cursor   = deg + N_NODES;                    // [N]   (zeroed)
    unsigned int* off      = cursor + N_NODES;                 // [N+1]
    unsigned int* edge_src = off + (N_NODES + 1);              // [E]
    unsigned short* Wp     = (unsigned short*)(edge_src + N_EDGES); // [65536] bf16

    hipMemsetAsync(d_ws, 0, 2 * (size_t)N_NODES * sizeof(unsigned int), stream);

    degree_count<<<dim3((N_EDGES + 255) / 256), dim3(256), 0, stream>>>(receivers, deg);
    scan_offsets<<<dim3(1), dim3(1024), 0, stream>>>(deg, off);
    csr_fill<<<dim3((N_EDGES + 255) / 256), dim3(256), 0, stream>>>(
        senders, receivers, off, cursor, edge_src);
    repack_w<<<dim3(65536 / 256), dim3(256), 0, stream>>>(W, Wp);

    int gemm_blocks = (N_NODES + 63) / 64;   // 782
    gather_mean_gemm<<<dim3(gemm_blocks), dim3(256), 0, stream>>>(
        nodes, off, edge_src, Wp, bias, out);
}

// Round 5
// 231.361 us; speedup vs baseline: 1.5657x; 1.2989x over previous
//
#include <hip/hip_runtime.h>
#include <hip/hip_bf16.h>

// Problem constants (from reference)
#define N_NODES 50000
#define D_FEAT  128
#define N_EDGES 600000
#define HIDDEN  256
#define K_DIM   256   // 2*D_FEAT

#define NCHUNK  196   // ceil(50000/256)

typedef __attribute__((ext_vector_type(8))) short bf16x8;   // 8 bf16 = 4 VGPRs
typedef __attribute__((ext_vector_type(4))) float f32x4;    // MFMA acc

__device__ __forceinline__ unsigned short f32_to_bf16(float f) {
    unsigned int u = __float_as_uint(f);
    unsigned int r = (u + 0x7fffu + ((u >> 16) & 1u)) >> 16;  // RNE
    return (unsigned short)r;
}
__device__ __forceinline__ unsigned int pack_bf16x2(float lo, float hi) {
    return (unsigned int)f32_to_bf16(lo) | ((unsigned int)f32_to_bf16(hi) << 16);
}
__device__ __forceinline__ float bf_lo(unsigned int v) {
    return __uint_as_float(v << 16);
}
__device__ __forceinline__ float bf_hi(unsigned int v) {
    return __uint_as_float(v & 0xffff0000u);
}

// ---------------------------------------------------------------------------
// K1: convert nodes f32 [N,128] -> packed bf16x2 [N,64] u32
// ---------------------------------------------------------------------------
__global__ __launch_bounds__(256) void conv_nodes(
    const float* __restrict__ nodes, unsigned int* __restrict__ nb) {
    int p = blockIdx.x * 256 + threadIdx.x;        // pair index < N*64
    if (p < N_NODES * 64) {
        const float2 v = *(const float2*)(nodes + (size_t)p * 2);
        nb[p] = pack_bf16x2(v.x, v.y);
    }
}

// ---------------------------------------------------------------------------
// K2: per-receiver degree count
// ---------------------------------------------------------------------------
__global__ __launch_bounds__(256) void degree_count(
    const int* __restrict__ receivers, unsigned int* __restrict__ deg) {
    int e = blockIdx.x * 256 + threadIdx.x;
    if (e < N_EDGES) atomicAdd(&deg[receivers[e]], 1u);
}

// ---------------------------------------------------------------------------
// K3a: per-256-node-chunk degree sums (196 blocks)
// ---------------------------------------------------------------------------
__global__ __launch_bounds__(256) void chunk_sums(
    const unsigned int* __restrict__ deg, unsigned int* __restrict__ bsum) {
    __shared__ unsigned int part[256];
    int t = threadIdx.x;
    int i = blockIdx.x * 256 + t;
    part[t] = (i < N_NODES) ? deg[i] : 0u;
    __syncthreads();
    for (int s = 128; s > 0; s >>= 1) {
        if (t < s) part[t] += part[t + s];
        __syncthreads();
    }
    if (t == 0) bsum[blockIdx.x] = part[0];
}

// ---------------------------------------------------------------------------
// K3b: exclusive scan of the 196 chunk sums (1 tiny block)
// ---------------------------------------------------------------------------
__global__ __launch_bounds__(256) void scan_bsums(
    const unsigned int* __restrict__ bsum, unsigned int* __restrict__ bbase) {
    __shared__ unsigned int part[256];
    int t = threadIdx.x;
    unsigned int own = (t < NCHUNK) ? bsum[t] : 0u;
    part[t] = own;
    __syncthreads();
    for (int d = 1; d < 256; d <<= 1) {
        unsigned int v = (t >= d) ? part[t - d] : 0u;
        __syncthreads();
        part[t] += v;
        __syncthreads();
    }
    if (t < NCHUNK) bbase[t] = part[t] - own;   // exclusive
}

// ---------------------------------------------------------------------------
// K3c: fill off[] (196 blocks, local LDS scan + chunk base).
// Also zeroes deg[] afterwards so csr_fill can reuse it as its cursor.
// ---------------------------------------------------------------------------
__global__ __launch_bounds__(256) void fill_offsets(
    const unsigned int* __restrict__ deg_in, const unsigned int* __restrict__ bbase,
    unsigned int* __restrict__ off, unsigned int* __restrict__ deg_clear) {
    __shared__ unsigned int part[256];
    int t = threadIdx.x;
    int i = blockIdx.x * 256 + t;
    unsigned int own = (i < N_NODES) ? deg_in[i] : 0u;
    part[t] = own;
    __syncthreads();
    for (int d = 1; d < 256; d <<= 1) {
        unsigned int v = (t >= d) ? part[t - d] : 0u;
        __syncthreads();
        part[t] += v;
        __syncthreads();
    }
    if (i < N_NODES) {
        off[i] = bbase[blockIdx.x] + part[t] - own;   // exclusive
        deg_clear[i] = 0u;                            // cursor for csr_fill
    }
    if (blockIdx.x == 0 && t == 0) off[N_NODES] = N_EDGES;  // degrees sum to E
}

// ---------------------------------------------------------------------------
// K4: CSR fill (cursor = reused deg buffer, zeroed by fill_offsets)
// ---------------------------------------------------------------------------
__global__ __launch_bounds__(256) void csr_fill(
    const int* __restrict__ senders, const int* __restrict__ receivers,
    const unsigned int* __restrict__ off, unsigned int* __restrict__ cursor,
    unsigned int* __restrict__ edge_src) {
    int e = blockIdx.x * 256 + threadIdx.x;
    if (e < N_EDGES) {
        int r = receivers[e];
        unsigned int slot = atomicAdd(&cursor[r], 1u);
        edge_src[off[r] + slot] = (unsigned int)senders[e];
    }
}

// ---------------------------------------------------------------------------
// K5: repack W (f32 [256][256] row-major) into bf16 MFMA-B-fragment order:
// Wp[kt][n][quad][j]  (kt<8, n<256, quad<4, j<8), k = kt*32 + quad*8 + j.
// ---------------------------------------------------------------------------
__global__ __launch_bounds__(256) void repack_w(
    const float* __restrict__ W, unsigned short* __restrict__ Wp) {
    int t = blockIdx.x * 256 + threadIdx.x;      // 65536 total
    int kt = t >> 13;
    int n  = (t >> 5) & 255;
    int q  = (t >> 3) & 3;
    int j  = t & 7;
    int k  = kt * 32 + q * 8 + j;
    Wp[t] = f32_to_bf16(W[k * 256 + n]);
}

// ---------------------------------------------------------------------------
// K6: fused CSR-gather mean (bf16 rows) + concat + MFMA GEMM + bias + relu.
// Block: 256 threads (4 waves), tile = 32 nodes x 256 hidden (grid 1563 ->
// ~6 blocks/CU, LDS 16.9 KB). Phase A: wave w owns rows [w*8, w*8+8);
// 8-deep unrolled bf16x2 gather (4B/lane/edge), f32 accumulate.
// Phase B: 2x4 tiles of mfma_f32_16x16x32_bf16 over K=256.
// h row stride 264 u16 (132 u32): 2-way bank alias only (free).
// ---------------------------------------------------------------------------
#define H_STRIDE 264   // u16 units; 132 u32 units
#define M_TILE   32

__global__ __launch_bounds__(256) void gather_mean_gemm(
    const unsigned int* __restrict__ nb,       // packed bf16 nodes [N*64]
    const unsigned int* __restrict__ off,
    const unsigned int* __restrict__ edge_src,
    const unsigned short* __restrict__ Wp,
    const float* __restrict__ bias,
    float* __restrict__ out) {
    __shared__ __align__(16) unsigned int h32[M_TILE * (H_STRIDE / 2)];

    const int m0   = blockIdx.x * M_TILE;
    const int tid  = threadIdx.x;
    const int wave = tid >> 6;
    const int lane = tid & 63;

    // ---- Phase A: gather + mean + self-features into LDS ----
    for (int i = 0; i < 8; i++) {
        int row = wave * 8 + i;
        int m   = m0 + row;
        float s0 = 0.f, s1 = 0.f, p0 = 0.f, p1 = 0.f;
        float q0 = 0.f, q1 = 0.f, r0 = 0.f, r1 = 0.f;
        unsigned int selfp = 0u;
        unsigned int degv  = 0u;
        if (m < N_NODES) {
            unsigned int eb = off[m], ee = off[m + 1];
            degv = ee - eb;
            unsigned int e = eb;
            for (; e + 8 <= ee; e += 8) {
                unsigned int i0 = edge_src[e + 0], i1 = edge_src[e + 1];
                unsigned int i2 = edge_src[e + 2], i3 = edge_src[e + 3];
                unsigned int i4 = edge_src[e + 4], i5 = edge_src[e + 5];
                unsigned int i6 = edge_src[e + 6], i7 = edge_src[e + 7];
                unsigned int v0 = nb[(size_t)i0 * 64 + lane];
                unsigned int v1 = nb[(size_t)i1 * 64 + lane];
                unsigned int v2 = nb[(size_t)i2 * 64 + lane];
                unsigned int v3 = nb[(size_t)i3 * 64 + lane];
                unsigned int v4 = nb[(size_t)i4 * 64 + lane];
                unsigned int v5 = nb[(size_t)i5 * 64 + lane];
                unsigned int v6 = nb[(size_t)i6 * 64 + lane];
                unsigned int v7 = nb[(size_t)i7 * 64 + lane];
                s0 += bf_lo(v0); s1 += bf_hi(v0); p0 += bf_lo(v1); p1 += bf_hi(v1);
                q0 += bf_lo(v2); q1 += bf_hi(v2); r0 += bf_lo(v3); r1 += bf_hi(v3);
                s0 += bf_lo(v4); s1 += bf_hi(v4); p0 += bf_lo(v5); p1 += bf_hi(v5);
                q0 += bf_lo(v6); q1 += bf_hi(v6); r0 += bf_lo(v7); r1 += bf_hi(v7);
            }
            for (; e + 4 <= ee; e += 4) {
                unsigned int i0 = edge_src[e + 0], i1 = edge_src[e + 1];
                unsigned int i2 = edge_src[e + 2], i3 = edge_src[e + 3];
                unsigned int v0 = nb[(size_t)i0 * 64 + lane];
                unsigned int v1 = nb[(size_t)i1 * 64 + lane];
                unsigned int v2 = nb[(size_t)i2 * 64 + lane];
                unsigned int v3 = nb[(size_t)i3 * 64 + lane];
                s0 += bf_lo(v0); s1 += bf_hi(v0); p0 += bf_lo(v1); p1 += bf_hi(v1);
                q0 += bf_lo(v2); q1 += bf_hi(v2); r0 += bf_lo(v3); r1 += bf_hi(v3);
            }
            for (; e < ee; e++) {
                unsigned int v0 = nb[(size_t)edge_src[e] * 64 + lane];
                s0 += bf_lo(v0); s1 += bf_hi(v0);
            }
            selfp = nb[(size_t)m * 64 + lane];
        }
        float inv = 1.0f / fmaxf((float)degv, 1.0f);
        float a0 = (s0 + p0 + q0 + r0) * inv;
        float a1 = (s1 + p1 + q1 + r1) * inv;
        h32[row * (H_STRIDE / 2) + lane]      = pack_bf16x2(a0, a1);
        h32[row * (H_STRIDE / 2) + 64 + lane] = selfp;
    }
    __syncthreads();

    // ---- Phase B: MFMA GEMM ----
    const unsigned short* h = (const unsigned short*)h32;
    const int nbase = wave * 64;
    const int rsel  = lane & 15;   // n (B/D) or m (A) within 16
    const int quad  = lane >> 4;   // k-group / row-group selector

    f32x4 acc[2][4] = {};

    for (int kk = 0; kk < K_DIM; kk += 32) {
        bf16x8 a[2], bw[4];
        #pragma unroll
        for (int mt = 0; mt < 2; mt++) {
            const unsigned short* pa =
                &h[(mt * 16 + rsel) * H_STRIDE + kk + quad * 8];
            a[mt] = *(const bf16x8*)pa;   // ds_read_b128
        }
        int kt = kk >> 5;
        #pragma unroll
        for (int nt = 0; nt < 4; nt++) {
            int n = nbase + nt * 16 + rsel;
            bw[nt] = *(const bf16x8*)&Wp[kt * 8192 + n * 32 + quad * 8];
        }
        #pragma unroll
        for (int mt = 0; mt < 2; mt++)
            #pragma unroll
            for (int nt = 0; nt < 4; nt++)
                acc[mt][nt] = __builtin_amdgcn_mfma_f32_16x16x32_bf16(
                    a[mt], bw[nt], acc[mt][nt], 0, 0, 0);
    }

    // epilogue: bias + relu, f32 store.  C/D: col(n)=lane&15, row(m)=quad*4+reg
    #pragma unroll
    for (int nt = 0; nt < 4; nt++) {
        int n = nbase + nt * 16 + rsel;
        float bn = bias[n];
        #pragma unroll
        for (int mt = 0; mt < 2; mt++) {
            #pragma unroll
            for (int r = 0; r < 4; r++) {
                int m = m0 + mt * 16 + quad * 4 + r;
                if (m < N_NODES) {
                    float v = acc[mt][nt][r] + bn;
                    out[(size_t)m * HIDDEN + n] = fmaxf(v, 0.0f);
                }
            }
        }
    }
}

// ---------------------------------------------------------------------------
extern "C" void kernel_launch(void* const* d_in, const int* in_sizes, int n_in,
                              void* d_out, int out_size, void* d_ws, size_t ws_size,
                              hipStream_t stream) {
    const float* nodes     = (const float*)d_in[0];   // f32 [N,128]
    const int*   senders   = (const int*)d_in[1];     // [E]
    const int*   receivers = (const int*)d_in[2];     // [E]
    const float* W         = (const float*)d_in[3];   // f32 [256,256]
    const float* bias      = (const float*)d_in[4];   // f32 [256]
    float*       out       = (float*)d_out;           // f32 [N,256]

    // workspace layout (~15.7 MB total)
    unsigned int* deg      = (unsigned int*)d_ws;               // [N] (also cursor)
    unsigned int* off      = deg + N_NODES;                     // [N+1]
    unsigned int* bsum     = off + (N_NODES + 1);               // [196]
    unsigned int* bbase    = bsum + NCHUNK;                     // [196]
    unsigned int* edge_src = bbase + NCHUNK;                    // [E]
    unsigned int* nodesb   = edge_src + N_EDGES;                // [N*64] packed bf16x2
    unsigned short* Wp     = (unsigned short*)(nodesb + (size_t)N_NODES * 64);

    hipMemsetAsync(deg, 0, (size_t)N_NODES * sizeof(unsigned int), stream);

    conv_nodes<<<dim3((N_NODES * 64 + 255) / 256), dim3(256), 0, stream>>>(nodes, nodesb);
    degree_count<<<dim3((N_EDGES + 255) / 256), dim3(256), 0, stream>>>(receivers, deg);
    chunk_sums<<<dim3(NCHUNK), dim3(256), 0, stream>>>(deg, bsum);
    scan_bsums<<<dim3(1), dim3(256), 0, stream>>>(bsum, bbase);
    fill_offsets<<<dim3(NCHUNK), dim3(256), 0, stream>>>(deg, bbase, off, deg);
    csr_fill<<<dim3((N_EDGES + 255) / 256), dim3(256), 0, stream>>>(
        senders, receivers, off, deg /*cursor*/, edge_src);
    repack_w<<<dim3(65536 / 256), dim3(256), 0, stream>>>(W, Wp);

    int gemm_blocks = (N_NODES + M_TILE - 1) / M_TILE;   // 1563
    gather_mean_gemm<<<dim3(gemm_blocks), dim3(256), 0, stream>>>(
        nodesb, off, edge_src, Wp, bias, out);
}